// Round 7
// baseline (295.720 us; speedup 1.0000x reference)
//
#include <hip/hip_runtime.h>

typedef __bf16 bf16;
typedef __bf16 bf16x4 __attribute__((ext_vector_type(4)));
typedef __bf16 bf16x8 __attribute__((ext_vector_type(8)));
typedef float f32x4 __attribute__((ext_vector_type(4)));

#define NROWS 32768   // B*S = 32*1024
#define EMBED 512
#define CONV_C 512
#define HID 1024
#define LABELS 128

__device__ inline void async16(const void* g, void* l) {
  __builtin_amdgcn_global_load_lds(
      (const __attribute__((address_space(1))) void*)g,
      (__attribute__((address_space(3))) void*)l, 16, 0, 0);
}

// h_tile pos: row stride 512 bf16 (64 x 16B chunks), XOR low-3 chunk bits
__device__ inline int hpos(int row, int chunk) {
  return (chunk & 56) | ((chunk & 7) ^ (row & 7));
}
// zbuf pos: row stride 128 bf16 (16 x 16B chunks)
__device__ inline int zpos(int row, int chunk) {
  return (chunk & 8) | ((chunk & 7) ^ (row & 7));
}

// two 16B fp32 chunks (swizzled positions) -> bf16x8 fragment
__device__ inline bf16x8 cvt8_sw(const float* row, int o0, int o1) {
  f32x4 lo = *(const f32x4*)(row + o0);
  f32x4 hi = *(const f32x4*)(row + o1);
  bf16x8 r;
  r[0] = (bf16)lo[0]; r[1] = (bf16)lo[1]; r[2] = (bf16)lo[2]; r[3] = (bf16)lo[3];
  r[4] = (bf16)hi[0]; r[5] = (bf16)hi[1]; r[6] = (bf16)hi[2]; r[7] = (bf16)hi[3];
  return r;
}

// ---- prep kernels ----------------------------------------------------------

__global__ void cvt_bf16(const float* __restrict__ in, bf16* __restrict__ out, int n) {
  int i = (blockIdx.x * blockDim.x + threadIdx.x) * 4;
  if (i >= n) return;
  float4 v = *(const float4*)(in + i);
  bf16x4 o;
  o.x = (bf16)v.x; o.y = (bf16)v.y; o.z = (bf16)v.z; o.w = (bf16)v.w;
  *(bf16x4*)(out + i) = o;
}

// [K,N] f32 -> [N,K] bf16 transpose, 64x64 tiles
__global__ void transpose_cvt(const float* __restrict__ in, bf16* __restrict__ out,
                              int K, int N) {
  __shared__ float t[64][65];
  int kb = blockIdx.x * 64, nb = blockIdx.y * 64;
  for (int i = threadIdx.x; i < 4096; i += 256) {
    int r = i >> 6, c = i & 63;
    t[r][c] = in[(size_t)(kb + r) * N + nb + c];
  }
  __syncthreads();
  for (int i = threadIdx.x; i < 4096; i += 256) {
    int r = i >> 6, c = i & 63;
    out[(size_t)(nb + r) * K + kb + c] = (bf16)t[c][r];
  }
}

// ---- fully fused model -----------------------------------------------------
// One block = 128 rows. 8 waves (2m x 4n), grid 256 = 1 block/CU.
// LDS (160 KB):
//   [0,128K)    h_tile [128][512] bf16, chunk-XOR swizzled (hpos)
//   [128K,160K) phase1: A dbuf 2 x [128x32] f32 (16 KB each, emb gather)
//               phase2: zbuf [128][128] bf16 swizzled (zpos), 32 KB
// Phase 1 (h = relu(emb[tok] @ conv_w^T + b)): proven dbuf K-loop for the
//   gathered A (f32, 128B rows, 8-pos XOR, cvt8_sw); conv_w fragments read
//   DIRECT from global (L2-resident; 4 quads = contiguous 64B per row).
//   Epilogue writes relu -> h_tile (LDS), never to HBM.
// Phase 2 (out = relu(h@w1+b1)@w2+b2): per 256-wide z-chunk, K-loop over
//   h_tile with ZERO barriers and ZERO staging (A-frags straight from LDS,
//   w1t frags direct from global/L2). z -> zbuf in 128-k halves; layer 3
//   reads zbuf + w2t direct from global/L2.
__global__ __launch_bounds__(512, 2) void fused_model(
    const int* __restrict__ tok, const float* __restrict__ emb,
    const bf16* __restrict__ convw,   // [512][512] bf16 (channel-major)
    const float* __restrict__ conv_b,
    const bf16* __restrict__ w1t,     // [1024][512] bf16
    const float* __restrict__ b1,
    const bf16* __restrict__ w2t,     // [128][1024] bf16
    const float* __restrict__ b2,
    float* __restrict__ out) {
  __shared__ __attribute__((aligned(16))) char smem[163840];
  bf16* htile = (bf16*)smem;
  float* astage = (float*)(smem + 131072);
  bf16* zbuf = (bf16*)(smem + 131072);

  const int tid = threadIdx.x, wave = tid >> 6, lane = tid & 63;
  const int m0 = blockIdx.x * 128;
  const int am0 = (wave >> 2) * 64;   // wave m-offset (all phases)
  const int wn = wave & 3;            // wave n-group
  const int lb0 = wn * 32;            // wave label-offset (layer 3)
  const int lrow = lane & 15, quad = lane >> 4;

  // A staging geometry: [128x32] f32 = 1024 16B-slots; slot s = tid + c*512:
  // row = s>>3, p = s&7, src f32 col = (p ^ (row&7))*4  (proven R0-v1 family)
  int a_r[2], a_c[2];
#pragma unroll
  for (int c = 0; c < 2; ++c) {
    int s = tid + c * 512;
    a_r[c] = s >> 3;
    a_c[c] = ((s & 7) ^ (a_r[c] & 7)) * 4;
  }
  int trow[2];
#pragma unroll
  for (int c = 0; c < 2; ++c) trow[c] = tok[m0 + a_r[c]];

  auto stageA = [&](int p, int k0) {
    float* lAf = astage + p * 4096;
#pragma unroll
    for (int c = 0; c < 2; ++c)
      async16(emb + (size_t)trow[c] * EMBED + k0 + a_c[c],
              lAf + (size_t)(tid + c * 512) * 4);
  };

  const f32x4 zero4 = {0.f, 0.f, 0.f, 0.f};

  // ---------------- phase 1: h_tile = relu(emb @ convw^T + b) --------------
  for (int nc = 0; nc < 2; ++nc) {
    const int nc0 = nc * 256;
    stageA(0, 0);

    f32x4 acc[4][4];
#pragma unroll
    for (int i = 0; i < 4; ++i)
#pragma unroll
      for (int j = 0; j < 4; ++j) acc[i][j] = zero4;

    int cur = 0;
    for (int it = 0; it < 16; ++it) {
      __syncthreads();                  // A buf[cur] landed; prior reads fenced
      if (it < 15) stageA(cur ^ 1, (it + 1) * 32);
      const float* lAf = astage + cur * 4096;
      bf16x8 a[4], b[4];
#pragma unroll
      for (int t = 0; t < 4; ++t) {
        int r = am0 + t * 16 + lrow;
        int p0 = (2 * quad) ^ (r & 7);
        a[t] = cvt8_sw(lAf + r * 32, p0 * 4, (p0 ^ 1) * 4);
      }
#pragma unroll
      for (int t = 0; t < 4; ++t) {
        int row = nc0 + wn * 64 + t * 16 + lrow;
        b[t] = *(const bf16x8*)(convw + (size_t)row * EMBED + it * 32 + quad * 8);
      }
#pragma unroll
      for (int mi = 0; mi < 4; ++mi)
#pragma unroll
        for (int ni = 0; ni < 4; ++ni)
          acc[mi][ni] =
              __builtin_amdgcn_mfma_f32_16x16x32_bf16(a[mi], b[ni], acc[mi][ni], 0, 0, 0);
      cur ^= 1;
    }

    // epilogue: bias + relu -> h_tile (swizzled LDS)
#pragma unroll
    for (int mi = 0; mi < 4; ++mi) {
#pragma unroll
      for (int ni = 0; ni < 4; ++ni) {
        int col = nc0 + wn * 64 + ni * 16 + lrow;
        float bv = conv_b[col];
        int ch = col >> 3, cw = col & 7;
#pragma unroll
        for (int r = 0; r < 4; ++r) {
          int row = am0 + mi * 16 + quad * 4 + r;
          float v = acc[mi][ni][r] + bv;
          v = v > 0.f ? v : 0.f;
          htile[row * 512 + hpos(row, ch) * 8 + cw] = (bf16)v;
        }
      }
    }
  }
  __syncthreads();                      // h_tile fully visible; A DMA drained

  // ---------------- phase 2: out = relu(h@w1+b1)@w2 + b2 -------------------
  f32x4 out_acc[4][2];
#pragma unroll
  for (int i = 0; i < 4; ++i)
#pragma unroll
    for (int j = 0; j < 2; ++j) out_acc[i][j] = zero4;

  for (int chunk = 0; chunk < 4; ++chunk) {
    const int cn0 = chunk * 256;

    f32x4 z_acc[4][4];
#pragma unroll
    for (int i = 0; i < 4; ++i)
#pragma unroll
      for (int j = 0; j < 4; ++j) z_acc[i][j] = zero4;

    // barrier-free K-loop: A from h_tile (LDS), B direct from global (L2)
#pragma unroll
    for (int kt = 0; kt < 16; ++kt) {
      bf16x8 a[4], b[4];
#pragma unroll
      for (int t = 0; t < 4; ++t) {
        int r = am0 + t * 16 + lrow;
        int c = kt * 4 + quad;
        a[t] = *(const bf16x8*)(htile + r * 512 + hpos(r, c) * 8);
      }
#pragma unroll
      for (int t = 0; t < 4; ++t) {
        int row = cn0 + wn * 64 + t * 16 + lrow;
        b[t] = *(const bf16x8*)(w1t + (size_t)row * 512 + kt * 32 + quad * 8);
      }
#pragma unroll
      for (int mi = 0; mi < 4; ++mi)
#pragma unroll
        for (int ni = 0; ni < 4; ++ni)
          z_acc[mi][ni] =
              __builtin_amdgcn_mfma_f32_16x16x32_bf16(a[mi], b[ni], z_acc[mi][ni], 0, 0, 0);
    }

    // layer 3 in two 128-k halves through zbuf
#pragma unroll 1
    for (int half = 0; half < 2; ++half) {
      __syncthreads();                  // zbuf free (prior reads all fenced)
      if ((wn >> 1) == half) {
#pragma unroll
        for (int mi = 0; mi < 4; ++mi) {
#pragma unroll
          for (int ni = 0; ni < 4; ++ni) {
            int zc = wn * 64 + ni * 16 + lrow - half * 128;   // [0,128)
            float bv = b1[cn0 + wn * 64 + ni * 16 + lrow];
            int ch = zc >> 3, cw = zc & 7;
#pragma unroll
            for (int r = 0; r < 4; ++r) {
              int zrow = am0 + mi * 16 + quad * 4 + r;
              float v = z_acc[mi][ni][r] + bv;
              v = v > 0.f ? v : 0.f;
              zbuf[zrow * 128 + zpos(zrow, ch) * 8 + cw] = (bf16)v;
            }
          }
        }
      }
      __syncthreads();                  // zbuf visible to all waves
#pragma unroll
      for (int ks = 0; ks < 4; ++ks) {
        bf16x8 a3[4], b3[2];
#pragma unroll
        for (int t = 0; t < 4; ++t) {
          int r = am0 + t * 16 + lrow;
          int c = ks * 4 + quad;
          a3[t] = *(const bf16x8*)(zbuf + r * 128 + zpos(r, c) * 8);
        }
#pragma unroll
        for (int t = 0; t < 2; ++t) {
          int lab = lb0 + t * 16 + lrow;
          b3[t] = *(const bf16x8*)(w2t + (size_t)lab * HID + cn0 + half * 128 +
                                   ks * 32 + quad * 8);
        }
#pragma unroll
        for (int mi = 0; mi < 4; ++mi)
#pragma unroll
          for (int ni = 0; ni < 2; ++ni)
            out_acc[mi][ni] =
                __builtin_amdgcn_mfma_f32_16x16x32_bf16(a3[mi], b3[ni], out_acc[mi][ni], 0, 0, 0);
      }
    }
  }

  // epilogue: out = out_acc + b2
#pragma unroll
  for (int mi = 0; mi < 4; ++mi) {
#pragma unroll
    for (int ni = 0; ni < 2; ++ni) {
      int col = lb0 + ni * 16 + lrow;
      float bv = b2[col];
#pragma unroll
      for (int r = 0; r < 4; ++r) {
        int row = m0 + am0 + mi * 16 + quad * 4 + r;
        out[(size_t)row * LABELS + col] = out_acc[mi][ni][r] + bv;
      }
    }
  }
}

// ---- launcher --------------------------------------------------------------

extern "C" void kernel_launch(void* const* d_in, const int* in_sizes, int n_in,
                              void* d_out, int out_size, void* d_ws, size_t ws_size,
                              hipStream_t stream) {
  const int* tok = (const int*)d_in[0];
  const float* emb = (const float*)d_in[1];
  const float* conv_w = (const float*)d_in[2];  // [512,512] = [N,K]
  const float* conv_b = (const float*)d_in[3];
  const float* w1 = (const float*)d_in[4];      // [512,1024] = [K,N]
  const float* b1 = (const float*)d_in[5];
  const float* w2 = (const float*)d_in[6];      // [1024,128] = [K,N]
  const float* b2 = (const float*)d_in[7];
  float* out = (float*)d_out;

  char* ws = (char*)d_ws;
  bf16* wtc = (bf16*)(ws);                       // 512 KB [512,512]
  bf16* wt1 = (bf16*)(ws + (1u << 19));          // 1 MB   [1024,512]
  bf16* wt2 = (bf16*)(ws + 3 * (1u << 19));      // 256 KB [128,1024]

  // weight prep
  hipLaunchKernelGGL(cvt_bf16, dim3(256), dim3(256), 0, stream,
                     conv_w, wtc, CONV_C * EMBED);
  hipLaunchKernelGGL(transpose_cvt, dim3(8, 16), dim3(256), 0, stream,
                     w1, wt1, CONV_C, HID);
  hipLaunchKernelGGL(transpose_cvt, dim3(16, 2), dim3(256), 0, stream,
                     w2, wt2, HID, LABELS);

  // fully fused model: h never leaves LDS
  hipLaunchKernelGGL(fused_model, dim3(NROWS / 128), dim3(512),
                     0, stream, tok, emb, wtc, conv_b, wt1, b1, wt2, b2, out);
}